// Round 12
// baseline (404.102 us; speedup 1.0000x reference)
//
#include <hip/hip_runtime.h>
#include <hip/hip_bf16.h>
#include <cstddef>

#define NSTOCK 100
#define LOG2E 1.4426950408889634f

typedef _Float16 f16x8 __attribute__((ext_vector_type(8)));
typedef _Float16 f16x4 __attribute__((ext_vector_type(4)));
typedef float f32x16 __attribute__((ext_vector_type(16)));

static __device__ __forceinline__ float rcpf(float x){ return __builtin_amdgcn_rcpf(x); }
static __device__ __forceinline__ float exp2f_(float x){ return __builtin_amdgcn_exp2f(x); }

// ---------------------------------------------------------------------------
// prep: permuted+scaled weights Wp[480][144]  (round-8 layout, unchanged).
// slot p = n*32 + row (n=tile 0..14):  type = row&3, jjf = row>>2,
//   j = n*8 + (jjf&1)*4 + (jjf>>1)  -> thread (lhalf,p) owns 4 contiguous j.
// k: 0..15 x feats (W_ih), 16..135 h (W_hh), 136 = bias column, 137..143 0.
// Scale baked: sigmoid rows (i,f,o) * -log2e; tanh row (g) * +2log2e.
// ---------------------------------------------------------------------------
__global__ void prep_kernel(const float* __restrict__ W_ih,
                            const float* __restrict__ W_hh,
                            const float* __restrict__ b_ih,
                            const float* __restrict__ b_hh,
                            float* __restrict__ Wp) {
    int idx = blockIdx.x * 256 + threadIdx.x;
    if (idx < 480 * 144) {
        int k = idx % 144;
        int p = idx / 144;
        int n = p >> 5, row = p & 31, jjf = row >> 2, type = row & 3;
        int j = n * 8 + (jjf & 1) * 4 + (jjf >> 1);   // < 120
        int g = type * 120 + j;
        float scale = (type == 2) ? 2.f * LOG2E : -LOG2E;
        float v = 0.f;
        if (k < 136)       v = ((k < 16) ? W_ih[g * 16 + k] : W_hh[g * 120 + (k - 16)]) * scale;
        else if (k == 136) v = (b_ih[g] + b_hh[g]) * scale;   // bias col vs B==1
        Wp[idx] = v;
    }
}

// ---------------------------------------------------------------------------
// lstm: 200 blocks x 512 thr (8 waves, 2/SIMD via amdgpu_waves_per_eu(2,2)
// -> 256-reg budget). Waves 0..6 own N-tiles (2w, 2w+1); wave 7 owns tile 14
// + x staging. KEY: each wave reads the shared A-frags ONCE per 54 MFMAs --
// per-CU LDS reads halve vs round 11 (270->144 ds_read_b128/step), so the
// LDS pipe (was co-bound at ~3240cyc with the 3456cyc matrix pipe) is fully
// hidden. Two indep acc chains/wave cover dependent-MFMA latency at
// 2 waves/SIMD. Both tiles of wave w write kt=1+w (lanes l31 / l31+32).
// 3-term fp16-split MFMA (Wh*Ah + Wh*Al + Wl*Ah) == fp32 accuracy.
// ---------------------------------------------------------------------------
__global__ __launch_bounds__(512)
__attribute__((amdgpu_waves_per_eu(2, 2)))
void lstm_kernel(
        const float* __restrict__ x,
        const float* __restrict__ Wp,
        const float* __restrict__ w_lin,
        const float* __restrict__ b_lin,
        float* __restrict__ s_out) {
    __shared__ __align__(16) _Float16 AHi[2][9][64][8];
    __shared__ __align__(16) _Float16 ALo[2][9][64][8];
    __shared__ float sred[15][32];

    const int tid   = threadIdx.x;
    const int lane  = tid & 63;
    const int w     = tid >> 6;        // wave 0..7
    const int l31   = lane & 31;
    const int lhalf = lane >> 5;
    const int n0    = blockIdx.x * 32;

    const bool two = (w < 7);
    const int nt0 = two ? 2 * w : 14;  // even tile (14 is even)
    const int nt1 = 2 * w + 1;         // odd tile (valid only if two)

    // ---- persistent weight fragments: tile0 + (tile1 if two) ----
    f16x8 b0h[9], b0l[9], b1h[9], b1l[9];
    {
        const int p0 = nt0 * 32 + l31;
#pragma unroll
        for (int kt = 0; kt < 9; ++kt) {
            const float* wp = Wp + p0 * 144 + kt * 16 + lhalf * 8;
            f16x8 hi, lo;
#pragma unroll
            for (int e = 0; e < 8; ++e) {
                float v = wp[e];
                _Float16 h_ = (_Float16)v;
                hi[e] = h_; lo[e] = (_Float16)(v - (float)h_);
            }
            b0h[kt] = hi; b0l[kt] = lo;
        }
        if (two) {
            const int p1 = nt1 * 32 + l31;
#pragma unroll
            for (int kt = 0; kt < 9; ++kt) {
                const float* wp = Wp + p1 * 144 + kt * 16 + lhalf * 8;
                f16x8 hi, lo;
#pragma unroll
                for (int e = 0; e < 8; ++e) {
                    float v = wp[e];
                    _Float16 h_ = (_Float16)v;
                    hi[e] = h_; lo[e] = (_Float16)(v - (float)h_);
                }
                b1h[kt] = hi; b1l[kt] = lo;
            }
        }
    }

    // ---- zero h-region (kt 1..8) of both buffers: 512 threads, 2 iters ----
    {
        f16x8 z;
#pragma unroll
        for (int e = 0; e < 8; ++e) z[e] = (_Float16)0.f;
        for (int ii = tid; ii < 2 * 8 * 64; ii += 512) {
            int bf = ii >> 9, kt = 1 + ((ii >> 6) & 7), ln = ii & 63;
            *(f16x8*)&AHi[bf][kt][ln][0] = z;
            *(f16x8*)&ALo[bf][kt][ln][0] = z;
        }
    }
    __syncthreads();

    // ---- x staging geometry (wave 7): lane -> (row bx, half hx) ----
    const int bx = lane >> 1;
    const int hx = lane & 1;
    const int nx  = n0 + bx;
    const int bbx = nx / NSTOCK, ssx = nx % NSTOCK;
    const float* xbase = x + (size_t)bbx * 204800 + ssx * 16 + hx * 8;
    if (w == 7) {   // stage x_0 into buf 0
        float4 a0 = *(const float4*)xbase;
        float4 a1 = *(const float4*)(xbase + 4);
        float vv[8] = {a0.x, a0.y, a0.z, a0.w, a1.x, a1.y, a1.z, a1.w};
        f16x8 hi, lo;
#pragma unroll
        for (int e = 0; e < 8; ++e) {
            _Float16 h_ = (_Float16)vv[e];
            hi[e] = h_; lo[e] = (_Float16)(vv[e] - (float)h_);
        }
        *(f16x8*)&AHi[0][0][bx + 32 * hx][0] = hi;
        *(f16x8*)&ALo[0][0][bx + 32 * hx][0] = lo;
    }
    // ---- bias column: B[k=136][b] = 1.0, both buffers (kt8, ln 32+b, e 0;
    //      never overwritten: tile-14 h-writes hit kt8 lanes 0..31 only) ----
    if (tid < 64) {
        int buf = tid >> 5, b = tid & 31;
        AHi[buf][8][32 + b][0] = (_Float16)1.f;
    }
    __syncthreads();

    // ---- h-write constants: tile n -> kt = 1+(n>>1), ln = l31+32*(n&1),
    //      e = 4*lhalf+p.  Tiles (2w,2w+1) share kt = 1+w (wave7: 1+7=8). ----
    const int ktw = 1 + w;
    const int e0  = 4 * lhalf;

    float creg0[4] = {0.f, 0.f, 0.f, 0.f};
    float creg1[4] = {0.f, 0.f, 0.f, 0.f};

    for (int t = 0; t < 128; ++t) {
        const int rb = t & 1;
        const int wb = rb ^ 1;
        // ---- wave 7: issue x_{t+1} global loads early (hidden under GEMM) --
        float4 xa0, xa1;
        if (w == 7) {
            int tt = (t < 127) ? t + 1 : 127;
            const float* xp = xbase + (size_t)tt * 1600;
            xa0 = *(const float4*)xp;
            xa1 = *(const float4*)(xp + 4);
        }
        // ---- GEMM: 54 MFMA (wave7: 27), A-frags read ONCE per wave ----
        f32x16 acc0, acc1;
#pragma unroll
        for (int r = 0; r < 16; ++r) { acc0[r] = 0.f; acc1[r] = 0.f; }
#pragma unroll
        for (int kt = 0; kt < 9; ++kt) {
            f16x8 ah = *(const f16x8*)&AHi[rb][kt][lane][0];
            f16x8 al = *(const f16x8*)&ALo[rb][kt][lane][0];
            acc0 = __builtin_amdgcn_mfma_f32_32x32x16_f16(b0h[kt], ah, acc0, 0, 0, 0);
            if (two) acc1 = __builtin_amdgcn_mfma_f32_32x32x16_f16(b1h[kt], ah, acc1, 0, 0, 0);
            acc0 = __builtin_amdgcn_mfma_f32_32x32x16_f16(b0h[kt], al, acc0, 0, 0, 0);
            if (two) acc1 = __builtin_amdgcn_mfma_f32_32x32x16_f16(b1h[kt], al, acc1, 0, 0, 0);
            acc0 = __builtin_amdgcn_mfma_f32_32x32x16_f16(b0l[kt], ah, acc0, 0, 0, 0);
            if (two) acc1 = __builtin_amdgcn_mfma_f32_32x32x16_f16(b1l[kt], ah, acc1, 0, 0, 0);
        }
        // ---- wave 7: convert + write x_{t+1} into write buffer ----
        if (w == 7) {
            float vv[8] = {xa0.x, xa0.y, xa0.z, xa0.w, xa1.x, xa1.y, xa1.z, xa1.w};
            f16x8 hi, lo;
#pragma unroll
            for (int e = 0; e < 8; ++e) {
                _Float16 h_ = (_Float16)vv[e];
                hi[e] = h_; lo[e] = (_Float16)(vv[e] - (float)h_);
            }
            *(f16x8*)&AHi[wb][0][bx + 32 * hx][0] = hi;
            *(f16x8*)&ALo[wb][0][bx + 32 * hx][0] = lo;
        }
        // ---- lane-local activation + h-write, tile 0 (even: ln = l31) ----
        {
            f16x4 hi4, lo4;
#pragma unroll
            for (int p = 0; p < 4; ++p) {
                float iv = rcpf(1.f + exp2f_(acc0[4 * p + 0]));
                float fv = rcpf(1.f + exp2f_(acc0[4 * p + 1]));
                float gv = 1.f - 2.f * rcpf(1.f + exp2f_(acc0[4 * p + 2]));
                float ov = rcpf(1.f + exp2f_(acc0[4 * p + 3]));
                float c = fv * creg0[p] + iv * gv;
                creg0[p] = c;
                float h = ov * (1.f - 2.f * rcpf(1.f + exp2f_(c * 2.8853900817779268f)));
                _Float16 hh = (_Float16)h;
                hi4[p] = hh;
                lo4[p] = (_Float16)(h - (float)hh);
            }
            *(f16x4*)&AHi[wb][ktw][l31][e0] = hi4;
            *(f16x4*)&ALo[wb][ktw][l31][e0] = lo4;
        }
        // ---- tile 1 (odd: ln = l31 + 32), waves 0..6 only ----
        if (two) {
            f16x4 hi4, lo4;
#pragma unroll
            for (int p = 0; p < 4; ++p) {
                float iv = rcpf(1.f + exp2f_(acc1[4 * p + 0]));
                float fv = rcpf(1.f + exp2f_(acc1[4 * p + 1]));
                float gv = 1.f - 2.f * rcpf(1.f + exp2f_(acc1[4 * p + 2]));
                float ov = rcpf(1.f + exp2f_(acc1[4 * p + 3]));
                float c = fv * creg1[p] + iv * gv;
                creg1[p] = c;
                float h = ov * (1.f - 2.f * rcpf(1.f + exp2f_(c * 2.8853900817779268f)));
                _Float16 hh = (_Float16)h;
                hi4[p] = hh;
                lo4[p] = (_Float16)(h - (float)hh);
            }
            *(f16x4*)&AHi[wb][ktw][l31 + 32][e0] = hi4;
            *(f16x4*)&ALo[wb][ktw][l31 + 32][e0] = lo4;
        }
        __syncthreads();
    }

    // ---- s = h_last . w_lin + b_lin  (final h is in buffer 0) ----
    if (tid < 480) {
        const int b  = tid & 31;
        const int jg = tid >> 5;                 // 0..14, j = jg*8+e
        const int lane_ = b + 32 * (jg & 1);
        const int ktE = 1 + (jg >> 1);
        f16x8 hi = *(const f16x8*)&AHi[0][ktE][lane_][0];
        f16x8 lo = *(const f16x8*)&ALo[0][ktE][lane_][0];
        float sp = 0.f;
#pragma unroll
        for (int e = 0; e < 8; ++e)
            sp += ((float)hi[e] + (float)lo[e]) * w_lin[jg * 8 + e];
        sred[jg][b] = sp;
    }
    __syncthreads();
    if (tid < 32) {
        float s = b_lin[0];
#pragma unroll
        for (int jg2 = 0; jg2 < 15; ++jg2) s += sred[jg2][tid];
        s_out[n0 + tid] = s;
    }
}

// ---------------------------------------------------------------------------
// phat: 128 blocks = (b, i-half). fooT[m][b] transposed output.
// ---------------------------------------------------------------------------
__global__ __launch_bounds__(128) void phat_kernel(const float* __restrict__ s,
                                                   float* __restrict__ fooT) {
    __shared__ float a[NSTOCK], c[NSTOCK];
    const int b = blockIdx.x >> 1, half = blockIdx.x & 1, tid = threadIdx.x;
    const float* sb = s + b * NSTOCK;
    if (tid < NSTOCK) {
        float sj = sb[tid];
        float rs = 0.f;
        for (int i2 = 0; i2 < NSTOCK; ++i2) rs += fabsf(sj - sb[i2]);
        a[tid] = sj * 0.2f;
        c[tid] = rs * 0.2f;
    }
    __syncthreads();
    if (tid < 50) {
        const int i = half * 50 + tid;
        const float sci = (float)(99 - 2 * i);
        float m = -1e30f;
        for (int j = 0; j < NSTOCK; ++j) m = fmaxf(m, sci * a[j] - c[j]);
        float sum = 0.f;
        for (int j = 0; j < NSTOCK; ++j) sum += __expf(sci * a[j] - c[j] - m);
        const float inv = 1.f / sum;
        for (int j = 0; j < NSTOCK; ++j)
            fooT[(size_t)(i * NSTOCK + j) * 64 + b] = __expf(sci * a[j] - c[j] - m) * inv;
    }
}

// ---------------------------------------------------------------------------
// mlp1: partial sums z2Tp[half][u][b] = sum_{m in half} fooT[m][b]*W2[u][m]
// 128 blocks = (u-group of 4, m-half); 8 waves x 625-m chunks; LDS reduce.
// bias+relu+combine folded into mlp2.
// ---------------------------------------------------------------------------
__global__ __launch_bounds__(512) void mlp1_kernel(const float* __restrict__ fooT,
                                                   const float* __restrict__ W2,
                                                   float* __restrict__ z2Tp) {
    __shared__ float part[8][4][64];
    const int tid = threadIdx.x;
    const int wv = tid >> 6, lane = tid & 63;
    const int ug = blockIdx.x >> 1, half = blockIdx.x & 1;
    const int u0 = ug * 4;
    const int m0 = half * 5000 + wv * 625;
    float a0 = 0.f, a1 = 0.f, a2 = 0.f, a3 = 0.f;
    for (int mi = 0; mi < 625; ++mi) {
        int m = m0 + mi;
        float v = fooT[(size_t)m * 64 + lane];
        a0 += v * W2[(size_t)(u0 + 0) * 10000 + m];
        a1 += v * W2[(size_t)(u0 + 1) * 10000 + m];
        a2 += v * W2[(size_t)(u0 + 2) * 10000 + m];
        a3 += v * W2[(size_t)(u0 + 3) * 10000 + m];
    }
    part[wv][0][lane] = a0; part[wv][1][lane] = a1;
    part[wv][2][lane] = a2; part[wv][3][lane] = a3;
    __syncthreads();
    if (tid < 256) {
        int q = tid >> 6, b = tid & 63;
        float s = 0.f;
#pragma unroll
        for (int w2 = 0; w2 < 8; ++w2) s += part[w2][q][b];
        z2Tp[((size_t)half * 256 + (u0 + q)) * 64 + b] = s;
    }
}

// ---------------------------------------------------------------------------
// mlp2: zs[u] = relu(b2[u] + z2Tp[0][u][b] + z2Tp[1][u][b]);
//       z3[b][v] = sum_u zs[u]*W3[v][u] + b3[v]; out = softmax_v
// ---------------------------------------------------------------------------
__global__ __launch_bounds__(128) void mlp2_kernel(const float* __restrict__ z2Tp,
                                                   const float* __restrict__ b2,
                                                   const float* __restrict__ W3,
                                                   const float* __restrict__ b3,
                                                   float* __restrict__ out) {
    __shared__ float zs[256];
    __shared__ float logits[NSTOCK];
    const int b = blockIdx.x, tid = threadIdx.x;
    for (int u = tid; u < 256; u += 128) {
        float v = b2[u] + z2Tp[(size_t)u * 64 + b] + z2Tp[(size_t)(256 + u) * 64 + b];
        zs[u] = fmaxf(v, 0.f);
    }
    __syncthreads();
    if (tid < NSTOCK) {
        float acc = b3[tid];
        const float* wr = W3 + tid * 256;
        for (int u = 0; u < 256; ++u) acc += zs[u] * wr[u];
        logits[tid] = acc;
    }
    __syncthreads();
    if (tid < NSTOCK) {
        float m = -1e30f;
        for (int j = 0; j < NSTOCK; ++j) m = fmaxf(m, logits[j]);
        float sum = 0.f;
        for (int j = 0; j < NSTOCK; ++j) sum += __expf(logits[j] - m);
        out[b * NSTOCK + tid] = __expf(logits[tid] - m) / sum;
    }
}

// ---------------------------------------------------------------------------
extern "C" void kernel_launch(void* const* d_in, const int* in_sizes, int n_in,
                              void* d_out, int out_size, void* d_ws, size_t ws_size,
                              hipStream_t stream) {
    const float* x     = (const float*)d_in[0];
    const float* W_ih  = (const float*)d_in[1];
    const float* W_hh  = (const float*)d_in[2];
    const float* b_ih  = (const float*)d_in[3];
    const float* b_hh  = (const float*)d_in[4];
    const float* w_lin = (const float*)d_in[5];
    const float* b_lin = (const float*)d_in[6];
    const float* W2    = (const float*)d_in[7];
    const float* b2    = (const float*)d_in[8];
    const float* W3    = (const float*)d_in[9];
    const float* b3    = (const float*)d_in[10];

    float* ws    = (float*)d_ws;
    float* Wp    = ws;                 // 480*144 = 69120
    float* sbuf  = ws + 69600;         // 6400
    float* fooT  = ws + 76000;         // 10000*64 = 640000
    float* z2Tp  = ws + 716000;        // 2*256*64 = 32768
    float* out   = (float*)d_out;

    prep_kernel<<<271, 256, 0, stream>>>(W_ih, W_hh, b_ih, b_hh, Wp);
    lstm_kernel<<<200, 512, 0, stream>>>(x, Wp, w_lin, b_lin, sbuf);
    phat_kernel<<<128, 128, 0, stream>>>(sbuf, fooT);
    mlp1_kernel<<<128, 512, 0, stream>>>(fooT, W2, z2Tp);
    mlp2_kernel<<<64, 128, 0, stream>>>(z2Tp, b2, W3, b3, out);
}

// Round 13
// 302.232 us; speedup vs baseline: 1.3371x; 1.3371x over previous
//
#include <hip/hip_runtime.h>
#include <hip/hip_bf16.h>
#include <cstddef>

#define NSTOCK 100
#define LOG2E 1.4426950408889634f

typedef _Float16 f16x8 __attribute__((ext_vector_type(8)));
typedef _Float16 f16x4 __attribute__((ext_vector_type(4)));
typedef float f32x16 __attribute__((ext_vector_type(16)));

static __device__ __forceinline__ float rcpf(float x){ return __builtin_amdgcn_rcpf(x); }
static __device__ __forceinline__ float exp2f_(float x){ return __builtin_amdgcn_exp2f(x); }

// ---------------------------------------------------------------------------
// prep: permuted+scaled weights Wp[480][144]  (round-8 layout, unchanged).
// slot p = n*32 + row (n=tile 0..14):  type = row&3, jjf = row>>2,
//   j = n*8 + (jjf&1)*4 + (jjf>>1)  -> thread (lhalf,p) owns 4 contiguous j.
// k: 0..15 x feats (W_ih), 16..135 h (W_hh), 136 = bias column, 137..143 0.
// Scale baked: sigmoid rows (i,f,o) * -log2e; tanh row (g) * +2log2e.
// ---------------------------------------------------------------------------
__global__ void prep_kernel(const float* __restrict__ W_ih,
                            const float* __restrict__ W_hh,
                            const float* __restrict__ b_ih,
                            const float* __restrict__ b_hh,
                            float* __restrict__ Wp) {
    int idx = blockIdx.x * 256 + threadIdx.x;
    if (idx < 480 * 144) {
        int k = idx % 144;
        int p = idx / 144;
        int n = p >> 5, row = p & 31, jjf = row >> 2, type = row & 3;
        int j = n * 8 + (jjf & 1) * 4 + (jjf >> 1);   // < 120
        int g = type * 120 + j;
        float scale = (type == 2) ? 2.f * LOG2E : -LOG2E;
        float v = 0.f;
        if (k < 136)       v = ((k < 16) ? W_ih[g * 16 + k] : W_hh[g * 120 + (k - 16)]) * scale;
        else if (k == 136) v = (b_ih[g] + b_hh[g]) * scale;   // bias col vs B==1
        Wp[idx] = v;
    }
}

// ---------------------------------------------------------------------------
// lstm: r11 16-wave structure + fp16-h (2-term recurrent MFMA).
// 200 blocks x 1024 thr (16 waves, 4/SIMD), 32 batch rows/block.
// Wave 15 = x stager (x hi/lo in kt0/ALoX, double-buffered); h fp16-only in
// kt1-8; bias k=136. Per wave/step: 19 MFMA (was 27), 10 ds_read_b128 (was
// 18) -> per-CU MFMA 2280cyc, LDS 1800cyc (was 3240/3240 co-bound).
// Precision: W split Wh+Wl (exact to 2^-22); x split hi/lo (3-term, exact);
// h stored fp16 (~2^-11) but c stays f32 in regs and the s-epilogue uses
// f32 h partials -> only the in-recurrence h quantization remains.
// ---------------------------------------------------------------------------
__global__ __launch_bounds__(1024) void lstm_kernel(
        const float* __restrict__ x,
        const float* __restrict__ Wp,
        const float* __restrict__ w_lin,
        const float* __restrict__ b_lin,
        float* __restrict__ s_out) {
    __shared__ __align__(16) _Float16 AHi[2][9][64][8];   // kt0 = x(hi), kt1-8 = h, +bias
    __shared__ __align__(16) _Float16 ALoX[2][64][8];     // x lo part only
    __shared__ float sred[30][32];

    const int tid   = threadIdx.x;
    const int lane  = tid & 63;
    const int w     = tid >> 6;        // wave 0..15
    const int l31   = lane & 31;
    const int lhalf = lane >> 5;
    const int n0    = blockIdx.x * 32;

    // ---- persistent weight fragments (waves 0..14): A-operand ----
    f16x8 bh[9], bl[9];
    if (w < 15) {
        const int p = w * 32 + l31;
#pragma unroll
        for (int kt = 0; kt < 9; ++kt) {
            const float* wp = Wp + p * 144 + kt * 16 + lhalf * 8;
            f16x8 hi, lo;
#pragma unroll
            for (int e = 0; e < 8; ++e) {
                float v = wp[e];
                _Float16 h_ = (_Float16)v;
                hi[e] = h_;
                lo[e] = (_Float16)(v - (float)h_);
            }
            bh[kt] = hi; bl[kt] = lo;
        }
    }

    // ---- zero h-region (kt 1..8) of both buffers: 1024 threads, 1:1 ----
    {
        f16x8 z;
#pragma unroll
        for (int e = 0; e < 8; ++e) z[e] = (_Float16)0.f;
        int bf = tid >> 9, kt = 1 + ((tid >> 6) & 7), ln = tid & 63;
        *(f16x8*)&AHi[bf][kt][ln][0] = z;
    }
    __syncthreads();

    // ---- x staging geometry (wave 15): lane -> (row bx, half hx) ----
    const int bx = lane >> 1;
    const int hx = lane & 1;
    const int nx  = n0 + bx;
    const int bbx = nx / NSTOCK, ssx = nx % NSTOCK;
    const float* xbase = x + (size_t)bbx * 204800 + ssx * 16 + hx * 8;
    if (w == 15) {   // stage x_0 into buf 0
        float4 a0 = *(const float4*)xbase;
        float4 a1 = *(const float4*)(xbase + 4);
        float vv[8] = {a0.x, a0.y, a0.z, a0.w, a1.x, a1.y, a1.z, a1.w};
        f16x8 hi, lo;
#pragma unroll
        for (int e = 0; e < 8; ++e) {
            _Float16 h_ = (_Float16)vv[e];
            hi[e] = h_; lo[e] = (_Float16)(vv[e] - (float)h_);
        }
        *(f16x8*)&AHi[0][0][bx + 32 * hx][0] = hi;
        *(f16x8*)&ALoX[0][bx + 32 * hx][0] = lo;
    }
    // ---- bias column: B[k=136][b] = 1.0, both buffers (kt8, ln 32+b, e 0;
    //      never overwritten: wave-14 h-writes hit kt8 lanes 0..31 only) ----
    if (tid < 64) {
        int buf = tid >> 5, b = tid & 31;
        AHi[buf][8][32 + b][0] = (_Float16)1.f;
    }
    __syncthreads();

    // ---- h-write constants: thread owns j = w*8 + 4*lhalf + p (p=0..3),
    //      batch = l31 -> AHi[wb][1+(w>>1)][l31+32*(w&1)][4*lhalf+p] ----
    const int ktw = 1 + (w >> 1);
    const int lnw = l31 + 32 * (w & 1);
    const int e0  = 4 * lhalf;

    float creg[4] = {0.f, 0.f, 0.f, 0.f};
    float hlast[4] = {0.f, 0.f, 0.f, 0.f};

    for (int t = 0; t < 128; ++t) {
        const int rb = t & 1;
        const int wb = rb ^ 1;
        if (w == 15) {
            // ---- stage x_{t+1} into write buffer ----
            int tt = (t < 127) ? t + 1 : 127;
            const float* xp = xbase + (size_t)tt * 1600;
            float4 a0 = *(const float4*)xp;
            float4 a1 = *(const float4*)(xp + 4);
            float vv[8] = {a0.x, a0.y, a0.z, a0.w, a1.x, a1.y, a1.z, a1.w};
            f16x8 hi, lo;
#pragma unroll
            for (int e = 0; e < 8; ++e) {
                _Float16 h_ = (_Float16)vv[e];
                hi[e] = h_; lo[e] = (_Float16)(vv[e] - (float)h_);
            }
            *(f16x8*)&AHi[wb][0][bx + 32 * hx][0] = hi;
            *(f16x8*)&ALoX[wb][bx + 32 * hx][0] = lo;
        } else {
            // ---- GEMM: kt0 x (3-term) + kt1-8 h (2-term) = 19 MFMA ----
            f32x16 acc;
#pragma unroll
            for (int r = 0; r < 16; ++r) acc[r] = 0.f;
            {
                f16x8 ah = *(const f16x8*)&AHi[rb][0][lane][0];
                f16x8 al = *(const f16x8*)&ALoX[rb][lane][0];
                acc = __builtin_amdgcn_mfma_f32_32x32x16_f16(bh[0], ah, acc, 0, 0, 0);
                acc = __builtin_amdgcn_mfma_f32_32x32x16_f16(bh[0], al, acc, 0, 0, 0);
                acc = __builtin_amdgcn_mfma_f32_32x32x16_f16(bl[0], ah, acc, 0, 0, 0);
            }
#pragma unroll
            for (int kt = 1; kt < 9; ++kt) {
                f16x8 ah = *(const f16x8*)&AHi[rb][kt][lane][0];
                acc = __builtin_amdgcn_mfma_f32_32x32x16_f16(bh[kt], ah, acc, 0, 0, 0);
                acc = __builtin_amdgcn_mfma_f32_32x32x16_f16(bl[kt], ah, acc, 0, 0, 0);
            }
            // ---- lane-local activation (scales/sign baked in weights) ----
            f16x4 hi4;
#pragma unroll
            for (int p = 0; p < 4; ++p) {
                float iv = rcpf(1.f + exp2f_(acc[4 * p + 0]));
                float fv = rcpf(1.f + exp2f_(acc[4 * p + 1]));
                float gv = 1.f - 2.f * rcpf(1.f + exp2f_(acc[4 * p + 2]));
                float ov = rcpf(1.f + exp2f_(acc[4 * p + 3]));
                float c = fv * creg[p] + iv * gv;
                creg[p] = c;
                float h = ov * (1.f - 2.f * rcpf(1.f + exp2f_(c * 2.8853900817779268f)));
                hlast[p] = h;
                hi4[p] = (_Float16)h;
            }
            // ---- h-write: one contiguous 8B vector store ----
            *(f16x4*)&AHi[wb][ktw][lnw][e0] = hi4;
        }
        __syncthreads();
    }

    // ---- s = h_last . w_lin + b_lin  via f32 partials (no fp16 error) ----
    if (w < 15) {
        const int jb = w * 8 + 4 * lhalf;
        float sp = 0.f;
#pragma unroll
        for (int p = 0; p < 4; ++p) sp += w_lin[jb + p] * hlast[p];
        sred[w * 2 + lhalf][l31] = sp;
    }
    __syncthreads();
    if (tid < 32) {
        float s = b_lin[0];
#pragma unroll
        for (int r = 0; r < 30; ++r) s += sred[r][tid];
        s_out[n0 + tid] = s;
    }
}

// ---------------------------------------------------------------------------
// phat: 128 blocks = (b, i-half). fooT[m][b] transposed output.
// ---------------------------------------------------------------------------
__global__ __launch_bounds__(128) void phat_kernel(const float* __restrict__ s,
                                                   float* __restrict__ fooT) {
    __shared__ float a[NSTOCK], c[NSTOCK];
    const int b = blockIdx.x >> 1, half = blockIdx.x & 1, tid = threadIdx.x;
    const float* sb = s + b * NSTOCK;
    if (tid < NSTOCK) {
        float sj = sb[tid];
        float rs = 0.f;
        for (int i2 = 0; i2 < NSTOCK; ++i2) rs += fabsf(sj - sb[i2]);
        a[tid] = sj * 0.2f;
        c[tid] = rs * 0.2f;
    }
    __syncthreads();
    if (tid < 50) {
        const int i = half * 50 + tid;
        const float sci = (float)(99 - 2 * i);
        float m = -1e30f;
        for (int j = 0; j < NSTOCK; ++j) m = fmaxf(m, sci * a[j] - c[j]);
        float sum = 0.f;
        for (int j = 0; j < NSTOCK; ++j) sum += __expf(sci * a[j] - c[j] - m);
        const float inv = 1.f / sum;
        for (int j = 0; j < NSTOCK; ++j)
            fooT[(size_t)(i * NSTOCK + j) * 64 + b] = __expf(sci * a[j] - c[j] - m) * inv;
    }
}

// ---------------------------------------------------------------------------
// mlp1: partial sums z2Tp[half][u][b] = sum_{m in half} fooT[m][b]*W2[u][m]
// 128 blocks = (u-group of 4, m-half); 8 waves x 625-m chunks; LDS reduce.
// bias+relu+combine folded into mlp2.
// ---------------------------------------------------------------------------
__global__ __launch_bounds__(512) void mlp1_kernel(const float* __restrict__ fooT,
                                                   const float* __restrict__ W2,
                                                   float* __restrict__ z2Tp) {
    __shared__ float part[8][4][64];
    const int tid = threadIdx.x;
    const int wv = tid >> 6, lane = tid & 63;
    const int ug = blockIdx.x >> 1, half = blockIdx.x & 1;
    const int u0 = ug * 4;
    const int m0 = half * 5000 + wv * 625;
    float a0 = 0.f, a1 = 0.f, a2 = 0.f, a3 = 0.f;
    for (int mi = 0; mi < 625; ++mi) {
        int m = m0 + mi;
        float v = fooT[(size_t)m * 64 + lane];
        a0 += v * W2[(size_t)(u0 + 0) * 10000 + m];
        a1 += v * W2[(size_t)(u0 + 1) * 10000 + m];
        a2 += v * W2[(size_t)(u0 + 2) * 10000 + m];
        a3 += v * W2[(size_t)(u0 + 3) * 10000 + m];
    }
    part[wv][0][lane] = a0; part[wv][1][lane] = a1;
    part[wv][2][lane] = a2; part[wv][3][lane] = a3;
    __syncthreads();
    if (tid < 256) {
        int q = tid >> 6, b = tid & 63;
        float s = 0.f;
#pragma unroll
        for (int w2 = 0; w2 < 8; ++w2) s += part[w2][q][b];
        z2Tp[((size_t)half * 256 + (u0 + q)) * 64 + b] = s;
    }
}

// ---------------------------------------------------------------------------
// mlp2: zs[u] = relu(b2[u] + z2Tp[0][u][b] + z2Tp[1][u][b]);
//       z3[b][v] = sum_u zs[u]*W3[v][u] + b3[v]; out = softmax_v
// ---------------------------------------------------------------------------
__global__ __launch_bounds__(128) void mlp2_kernel(const float* __restrict__ z2Tp,
                                                   const float* __restrict__ b2,
                                                   const float* __restrict__ W3,
                                                   const float* __restrict__ b3,
                                                   float* __restrict__ out) {
    __shared__ float zs[256];
    __shared__ float logits[NSTOCK];
    const int b = blockIdx.x, tid = threadIdx.x;
    for (int u = tid; u < 256; u += 128) {
        float v = b2[u] + z2Tp[(size_t)u * 64 + b] + z2Tp[(size_t)(256 + u) * 64 + b];
        zs[u] = fmaxf(v, 0.f);
    }
    __syncthreads();
    if (tid < NSTOCK) {
        float acc = b3[tid];
        const float* wr = W3 + tid * 256;
        for (int u = 0; u < 256; ++u) acc += zs[u] * wr[u];
        logits[tid] = acc;
    }
    __syncthreads();
    if (tid < NSTOCK) {
        float m = -1e30f;
        for (int j = 0; j < NSTOCK; ++j) m = fmaxf(m, logits[j]);
        float sum = 0.f;
        for (int j = 0; j < NSTOCK; ++j) sum += __expf(logits[j] - m);
        out[b * NSTOCK + tid] = __expf(logits[tid] - m) / sum;
    }
}

// ---------------------------------------------------------------------------
extern "C" void kernel_launch(void* const* d_in, const int* in_sizes, int n_in,
                              void* d_out, int out_size, void* d_ws, size_t ws_size,
                              hipStream_t stream) {
    const float* x     = (const float*)d_in[0];
    const float* W_ih  = (const float*)d_in[1];
    const float* W_hh  = (const float*)d_in[2];
    const float* b_ih  = (const float*)d_in[3];
    const float* b_hh  = (const float*)d_in[4];
    const float* w_lin = (const float*)d_in[5];
    const float* b_lin = (const float*)d_in[6];
    const float* W2    = (const float*)d_in[7];
    const float* b2    = (const float*)d_in[8];
    const float* W3    = (const float*)d_in[9];
    const float* b3    = (const float*)d_in[10];

    float* ws    = (float*)d_ws;
    float* Wp    = ws;                 // 480*144 = 69120
    float* sbuf  = ws + 69600;         // 6400
    float* fooT  = ws + 76000;         // 10000*64 = 640000
    float* z2Tp  = ws + 716000;        // 2*256*64 = 32768
    float* out   = (float*)d_out;

    prep_kernel<<<271, 256, 0, stream>>>(W_ih, W_hh, b_ih, b_hh, Wp);
    lstm_kernel<<<200, 1024, 0, stream>>>(x, Wp, w_lin, b_lin, sbuf);
    phat_kernel<<<128, 128, 0, stream>>>(sbuf, fooT);
    mlp1_kernel<<<128, 512, 0, stream>>>(fooT, W2, z2Tp);
    mlp2_kernel<<<64, 128, 0, stream>>>(z2Tp, b2, W3, b3, out);
}

// Round 14
// 254.637 us; speedup vs baseline: 1.5870x; 1.1869x over previous
//
#include <hip/hip_runtime.h>
#include <hip/hip_bf16.h>
#include <cstddef>

#define NSTOCK 100
#define LOG2E 1.4426950408889634f

typedef _Float16 f16x8 __attribute__((ext_vector_type(8)));
typedef _Float16 f16x4 __attribute__((ext_vector_type(4)));
typedef float f32x16 __attribute__((ext_vector_type(16)));

static __device__ __forceinline__ float rcpf(float x){ return __builtin_amdgcn_rcpf(x); }
static __device__ __forceinline__ float exp2f_(float x){ return __builtin_amdgcn_exp2f(x); }

// ---------------------------------------------------------------------------
// prep: permuted+scaled weights Wp[480][144]  (round-8 layout, unchanged).
// slot p = n*32 + row (n=tile 0..14):  type = row&3, jjf = row>>2,
//   j = n*8 + (jjf&1)*4 + (jjf>>1)  -> thread (lhalf,p) owns 4 contiguous j.
// k: 0..15 x feats (W_ih), 16..135 h (W_hh), 136 = bias column, 137..143 0.
// Scale baked: sigmoid rows (i,f,o) * -log2e; tanh row (g) * +2log2e.
// ---------------------------------------------------------------------------
__global__ void prep_kernel(const float* __restrict__ W_ih,
                            const float* __restrict__ W_hh,
                            const float* __restrict__ b_ih,
                            const float* __restrict__ b_hh,
                            float* __restrict__ Wp) {
    int idx = blockIdx.x * 256 + threadIdx.x;
    if (idx < 480 * 144) {
        int k = idx % 144;
        int p = idx / 144;
        int n = p >> 5, row = p & 31, jjf = row >> 2, type = row & 3;
        int j = n * 8 + (jjf & 1) * 4 + (jjf >> 1);   // < 120
        int g = type * 120 + j;
        float scale = (type == 2) ? 2.f * LOG2E : -LOG2E;
        float v = 0.f;
        if (k < 136)       v = ((k < 16) ? W_ih[g * 16 + k] : W_hh[g * 120 + (k - 16)]) * scale;
        else if (k == 136) v = (b_ih[g] + b_hh[g]) * scale;   // bias col vs B==1
        Wp[idx] = v;
    }
}

// ---------------------------------------------------------------------------
// lstm: r13 structure + 1-term recurrent MFMA (fp16 W_hh).
// 200 blocks x 1024 thr (16 waves, 4/SIMD), 32 batch rows/block.
// Wave 15 = x stager (x hi/lo in kt0/ALoX, double-buffered); h fp16-only in
// kt1-8; bias k=136. Per wave/step: 11 MFMA (was 19) -- matrix pipe
// 1320cyc/SIMD, now clearly under the VALU (~2000) / LDS (~2000) budgets.
// Precision: x 3-term (exact); h-part single fp16 Whh*h (2^-11 systematic
// weight error -- same scale as r13's fp16-h quantization which measured
// absmax 0.0); c f32 in regs; s-epilogue f32 partials.
// ---------------------------------------------------------------------------
__global__ __launch_bounds__(1024) void lstm_kernel(
        const float* __restrict__ x,
        const float* __restrict__ Wp,
        const float* __restrict__ w_lin,
        const float* __restrict__ b_lin,
        float* __restrict__ s_out) {
    __shared__ __align__(16) _Float16 AHi[2][9][64][8];   // kt0 = x(hi), kt1-8 = h, +bias
    __shared__ __align__(16) _Float16 ALoX[2][64][8];     // x lo part only
    __shared__ float sred[30][32];

    const int tid   = threadIdx.x;
    const int lane  = tid & 63;
    const int w     = tid >> 6;        // wave 0..15
    const int l31   = lane & 31;
    const int lhalf = lane >> 5;
    const int n0    = blockIdx.x * 32;

    // ---- persistent weight fragments (waves 0..14): A-operand ----
    // bh[0..8] fp16-hi for all kt; bl0 = lo part for kt0 (x) only.
    f16x8 bh[9], bl0;
    if (w < 15) {
        const int p = w * 32 + l31;
#pragma unroll
        for (int kt = 0; kt < 9; ++kt) {
            const float* wp = Wp + p * 144 + kt * 16 + lhalf * 8;
            f16x8 hi, lo;
#pragma unroll
            for (int e = 0; e < 8; ++e) {
                float v = wp[e];
                _Float16 h_ = (_Float16)v;
                hi[e] = h_;
                lo[e] = (_Float16)(v - (float)h_);
            }
            bh[kt] = hi;
            if (kt == 0) bl0 = lo;
        }
    }

    // ---- zero h-region (kt 1..8) of both buffers: 1024 threads, 1:1 ----
    {
        f16x8 z;
#pragma unroll
        for (int e = 0; e < 8; ++e) z[e] = (_Float16)0.f;
        int bf = tid >> 9, kt = 1 + ((tid >> 6) & 7), ln = tid & 63;
        *(f16x8*)&AHi[bf][kt][ln][0] = z;
    }
    __syncthreads();

    // ---- x staging geometry (wave 15): lane -> (row bx, half hx) ----
    const int bx = lane >> 1;
    const int hx = lane & 1;
    const int nx  = n0 + bx;
    const int bbx = nx / NSTOCK, ssx = nx % NSTOCK;
    const float* xbase = x + (size_t)bbx * 204800 + ssx * 16 + hx * 8;
    if (w == 15) {   // stage x_0 into buf 0
        float4 a0 = *(const float4*)xbase;
        float4 a1 = *(const float4*)(xbase + 4);
        float vv[8] = {a0.x, a0.y, a0.z, a0.w, a1.x, a1.y, a1.z, a1.w};
        f16x8 hi, lo;
#pragma unroll
        for (int e = 0; e < 8; ++e) {
            _Float16 h_ = (_Float16)vv[e];
            hi[e] = h_; lo[e] = (_Float16)(vv[e] - (float)h_);
        }
        *(f16x8*)&AHi[0][0][bx + 32 * hx][0] = hi;
        *(f16x8*)&ALoX[0][bx + 32 * hx][0] = lo;
    }
    // ---- bias column: B[k=136][b] = 1.0, both buffers (kt8, ln 32+b, e 0;
    //      never overwritten: wave-14 h-writes hit kt8 lanes 0..31 only) ----
    if (tid < 64) {
        int buf = tid >> 5, b = tid & 31;
        AHi[buf][8][32 + b][0] = (_Float16)1.f;
    }
    __syncthreads();

    // ---- h-write constants: thread owns j = w*8 + 4*lhalf + p (p=0..3),
    //      batch = l31 -> AHi[wb][1+(w>>1)][l31+32*(w&1)][4*lhalf+p] ----
    const int ktw = 1 + (w >> 1);
    const int lnw = l31 + 32 * (w & 1);
    const int e0  = 4 * lhalf;

    float creg[4] = {0.f, 0.f, 0.f, 0.f};
    float hlast[4] = {0.f, 0.f, 0.f, 0.f};

    for (int t = 0; t < 128; ++t) {
        const int rb = t & 1;
        const int wb = rb ^ 1;
        if (w == 15) {
            // ---- stage x_{t+1} into write buffer ----
            int tt = (t < 127) ? t + 1 : 127;
            const float* xp = xbase + (size_t)tt * 1600;
            float4 a0 = *(const float4*)xp;
            float4 a1 = *(const float4*)(xp + 4);
            float vv[8] = {a0.x, a0.y, a0.z, a0.w, a1.x, a1.y, a1.z, a1.w};
            f16x8 hi, lo;
#pragma unroll
            for (int e = 0; e < 8; ++e) {
                _Float16 h_ = (_Float16)vv[e];
                hi[e] = h_; lo[e] = (_Float16)(vv[e] - (float)h_);
            }
            *(f16x8*)&AHi[wb][0][bx + 32 * hx][0] = hi;
            *(f16x8*)&ALoX[wb][bx + 32 * hx][0] = lo;
        } else {
            // ---- GEMM: kt0 x (3-term) + kt1-8 h (1-term) = 11 MFMA ----
            f32x16 acc;
#pragma unroll
            for (int r = 0; r < 16; ++r) acc[r] = 0.f;
            {
                f16x8 ah = *(const f16x8*)&AHi[rb][0][lane][0];
                f16x8 al = *(const f16x8*)&ALoX[rb][lane][0];
                acc = __builtin_amdgcn_mfma_f32_32x32x16_f16(bh[0], ah, acc, 0, 0, 0);
                acc = __builtin_amdgcn_mfma_f32_32x32x16_f16(bh[0], al, acc, 0, 0, 0);
                acc = __builtin_amdgcn_mfma_f32_32x32x16_f16(bl0, ah, acc, 0, 0, 0);
            }
#pragma unroll
            for (int kt = 1; kt < 9; ++kt) {
                f16x8 ah = *(const f16x8*)&AHi[rb][kt][lane][0];
                acc = __builtin_amdgcn_mfma_f32_32x32x16_f16(bh[kt], ah, acc, 0, 0, 0);
            }
            // ---- lane-local activation (scales/sign baked in weights) ----
            f16x4 hi4;
#pragma unroll
            for (int p = 0; p < 4; ++p) {
                float iv = rcpf(1.f + exp2f_(acc[4 * p + 0]));
                float fv = rcpf(1.f + exp2f_(acc[4 * p + 1]));
                float gv = 1.f - 2.f * rcpf(1.f + exp2f_(acc[4 * p + 2]));
                float ov = rcpf(1.f + exp2f_(acc[4 * p + 3]));
                float c = fv * creg[p] + iv * gv;
                creg[p] = c;
                float h = ov * (1.f - 2.f * rcpf(1.f + exp2f_(c * 2.8853900817779268f)));
                hlast[p] = h;
                hi4[p] = (_Float16)h;
            }
            // ---- h-write: one contiguous 8B vector store ----
            *(f16x4*)&AHi[wb][ktw][lnw][e0] = hi4;
        }
        __syncthreads();
    }

    // ---- s = h_last . w_lin + b_lin  via f32 partials (no fp16 error) ----
    if (w < 15) {
        const int jb = w * 8 + 4 * lhalf;
        float sp = 0.f;
#pragma unroll
        for (int p = 0; p < 4; ++p) sp += w_lin[jb + p] * hlast[p];
        sred[w * 2 + lhalf][l31] = sp;
    }
    __syncthreads();
    if (tid < 32) {
        float s = b_lin[0];
#pragma unroll
        for (int r = 0; r < 30; ++r) s += sred[r][tid];
        s_out[n0 + tid] = s;
    }
}

// ---------------------------------------------------------------------------
// phat: 128 blocks = (b, i-half). fooT[m][b] transposed output.
// ---------------------------------------------------------------------------
__global__ __launch_bounds__(128) void phat_kernel(const float* __restrict__ s,
                                                   float* __restrict__ fooT) {
    __shared__ float a[NSTOCK], c[NSTOCK];
    const int b = blockIdx.x >> 1, half = blockIdx.x & 1, tid = threadIdx.x;
    const float* sb = s + b * NSTOCK;
    if (tid < NSTOCK) {
        float sj = sb[tid];
        float rs = 0.f;
        for (int i2 = 0; i2 < NSTOCK; ++i2) rs += fabsf(sj - sb[i2]);
        a[tid] = sj * 0.2f;
        c[tid] = rs * 0.2f;
    }
    __syncthreads();
    if (tid < 50) {
        const int i = half * 50 + tid;
        const float sci = (float)(99 - 2 * i);
        float m = -1e30f;
        for (int j = 0; j < NSTOCK; ++j) m = fmaxf(m, sci * a[j] - c[j]);
        float sum = 0.f;
        for (int j = 0; j < NSTOCK; ++j) sum += __expf(sci * a[j] - c[j] - m);
        const float inv = 1.f / sum;
        for (int j = 0; j < NSTOCK; ++j)
            fooT[(size_t)(i * NSTOCK + j) * 64 + b] = __expf(sci * a[j] - c[j] - m) * inv;
    }
}

// ---------------------------------------------------------------------------
// mlp1: partial sums z2Tp[half][u][b] = sum_{m in half} fooT[m][b]*W2[u][m]
// 128 blocks = (u-group of 4, m-half); 8 waves x 625-m chunks; LDS reduce.
// bias+relu+combine folded into mlp2.
// ---------------------------------------------------------------------------
__global__ __launch_bounds__(512) void mlp1_kernel(const float* __restrict__ fooT,
                                                   const float* __restrict__ W2,
                                                   float* __restrict__ z2Tp) {
    __shared__ float part[8][4][64];
    const int tid = threadIdx.x;
    const int wv = tid >> 6, lane = tid & 63;
    const int ug = blockIdx.x >> 1, half = blockIdx.x & 1;
    const int u0 = ug * 4;
    const int m0 = half * 5000 + wv * 625;
    float a0 = 0.f, a1 = 0.f, a2 = 0.f, a3 = 0.f;
    for (int mi = 0; mi < 625; ++mi) {
        int m = m0 + mi;
        float v = fooT[(size_t)m * 64 + lane];
        a0 += v * W2[(size_t)(u0 + 0) * 10000 + m];
        a1 += v * W2[(size_t)(u0 + 1) * 10000 + m];
        a2 += v * W2[(size_t)(u0 + 2) * 10000 + m];
        a3 += v * W2[(size_t)(u0 + 3) * 10000 + m];
    }
    part[wv][0][lane] = a0; part[wv][1][lane] = a1;
    part[wv][2][lane] = a2; part[wv][3][lane] = a3;
    __syncthreads();
    if (tid < 256) {
        int q = tid >> 6, b = tid & 63;
        float s = 0.f;
#pragma unroll
        for (int w2 = 0; w2 < 8; ++w2) s += part[w2][q][b];
        z2Tp[((size_t)half * 256 + (u0 + q)) * 64 + b] = s;
    }
}

// ---------------------------------------------------------------------------
// mlp2: zs[u] = relu(b2[u] + z2Tp[0][u][b] + z2Tp[1][u][b]);
//       z3[b][v] = sum_u zs[u]*W3[v][u] + b3[v]; out = softmax_v
// ---------------------------------------------------------------------------
__global__ __launch_bounds__(128) void mlp2_kernel(const float* __restrict__ z2Tp,
                                                   const float* __restrict__ b2,
                                                   const float* __restrict__ W3,
                                                   const float* __restrict__ b3,
                                                   float* __restrict__ out) {
    __shared__ float zs[256];
    __shared__ float logits[NSTOCK];
    const int b = blockIdx.x, tid = threadIdx.x;
    for (int u = tid; u < 256; u += 128) {
        float v = b2[u] + z2Tp[(size_t)u * 64 + b] + z2Tp[(size_t)(256 + u) * 64 + b];
        zs[u] = fmaxf(v, 0.f);
    }
    __syncthreads();
    if (tid < NSTOCK) {
        float acc = b3[tid];
        const float* wr = W3 + tid * 256;
        for (int u = 0; u < 256; ++u) acc += zs[u] * wr[u];
        logits[tid] = acc;
    }
    __syncthreads();
    if (tid < NSTOCK) {
        float m = -1e30f;
        for (int j = 0; j < NSTOCK; ++j) m = fmaxf(m, logits[j]);
        float sum = 0.f;
        for (int j = 0; j < NSTOCK; ++j) sum += __expf(logits[j] - m);
        out[b * NSTOCK + tid] = __expf(logits[tid] - m) / sum;
    }
}

// ---------------------------------------------------------------------------
extern "C" void kernel_launch(void* const* d_in, const int* in_sizes, int n_in,
                              void* d_out, int out_size, void* d_ws, size_t ws_size,
                              hipStream_t stream) {
    const float* x     = (const float*)d_in[0];
    const float* W_ih  = (const float*)d_in[1];
    const float* W_hh  = (const float*)d_in[2];
    const float* b_ih  = (const float*)d_in[3];
    const float* b_hh  = (const float*)d_in[4];
    const float* w_lin = (const float*)d_in[5];
    const float* b_lin = (const float*)d_in[6];
    const float* W2    = (const float*)d_in[7];
    const float* b2    = (const float*)d_in[8];
    const float* W3    = (const float*)d_in[9];
    const float* b3    = (const float*)d_in[10];

    float* ws    = (float*)d_ws;
    float* Wp    = ws;                 // 480*144 = 69120
    float* sbuf  = ws + 69600;         // 6400
    float* fooT  = ws + 76000;         // 10000*64 = 640000
    float* z2Tp  = ws + 716000;        // 2*256*64 = 32768
    float* out   = (float*)d_out;

    prep_kernel<<<271, 256, 0, stream>>>(W_ih, W_hh, b_ih, b_hh, Wp);
    lstm_kernel<<<200, 1024, 0, stream>>>(x, Wp, w_lin, b_lin, sbuf);
    phat_kernel<<<128, 128, 0, stream>>>(sbuf, fooT);
    mlp1_kernel<<<128, 512, 0, stream>>>(fooT, W2, z2Tp);
    mlp2_kernel<<<64, 128, 0, stream>>>(z2Tp, b2, W3, b3, out);
}